// Round 5
// baseline (663.197 us; speedup 1.0000x reference)
//
#include <hip/hip_runtime.h>

// ---------------------------------------------------------------------------
// ExtraPositionPromptSABottleneck on MI355X (gfx950)
// B=8, DIMS=512, C=256, H=W=64, N=4096.
//
// Round 5:
//  - gemm3b epilogue: butterfly (80 ds-ops/thread) replaced by LDS partial
//    matrix part[128][33] -> 16 writes + 32 reads, then 1 global atomic/row.
//  - gemm4 split-K (KS=2): grid 2x32x8 (512 blocks = 2/CU vs 1/CU before),
//    fp32 partials into the dead qp/ke region; reduce_norm kernel applies
//    1/lsum and emits bf16 out_t.
//  - LDS XOR swizzle retained (round 4: conflicts 8.4M -> 0).
// ---------------------------------------------------------------------------

typedef __bf16 bf16;
typedef __attribute__((ext_vector_type(8))) __bf16 bf16x8;
typedef __attribute__((ext_vector_type(4))) __bf16 bf16x4;
typedef __attribute__((ext_vector_type(4))) float f32x4;

__device__ __forceinline__ float silu_f(float x) { return x / (1.f + __expf(-x)); }

__device__ __forceinline__ void zero_acc(f32x4 (&acc)[4][4])
{
#pragma unroll
    for (int i = 0; i < 4; ++i)
#pragma unroll
        for (int j = 0; j < 4; ++j)
            acc[i][j] = (f32x4){0.f, 0.f, 0.f, 0.f};
}

// ---- LDS-staged GEMM core: block 256 thr, tile 128x128, BK=32
__device__ __forceinline__ void load_lds16(const bf16* g, bf16* l)
{
    __builtin_amdgcn_global_load_lds(
        (const __attribute__((address_space(1))) unsigned int*)g,
        (__attribute__((address_space(3))) unsigned int*)l, 16, 0, 0);
}

// A: block's 128 rows, k-contig stride lda. B: block's 128 "cols", stride ldb.
// LDS slot (row, kb) holds global (row, kb ^ ((row>>1)&3)) -- XOR swizzle.
__device__ __forceinline__ void gemm_core_lds(
    const bf16* __restrict__ A, int lda,
    const bf16* __restrict__ B, int ldb,
    int K, f32x4 (&acc)[4][4])
{
    __shared__ bf16 As[128 * 32];
    __shared__ bf16 Bs[128 * 32];
    const int tid = threadIdx.x;
    const int wave = tid >> 6;
    const int lane = tid & 63;
    const int lm = lane & 15;
    const int kq = lane >> 4;
    const int m0 = (wave >> 1) * 64;
    const int n0 = (wave & 1) * 64;
    // staging: each thread supplies 16B per round; 2 rounds per matrix.
    const int srow = tid >> 2;                              // rows 0..63, +64
    const int skoff = (((tid & 3) ^ ((tid >> 3) & 3))) * 8; // swizzled k-block
    const int krd = (kq ^ ((lm >> 1) & 3)) * 8;             // read-side offset
    bf16* lA = As + tid * 8;            // LDS dest = wave_base + lane*16B
    bf16* lB = Bs + tid * 8;
    zero_acc(acc);
    for (int k0 = 0; k0 < K; k0 += 32) {
        const bf16* ga = A + (size_t)srow * lda + k0 + skoff;
        const bf16* gb = B + (size_t)srow * ldb + k0 + skoff;
        load_lds16(ga, lA);
        load_lds16(ga + (size_t)64 * lda, lA + 64 * 32);
        load_lds16(gb, lB);
        load_lds16(gb + (size_t)64 * ldb, lB + 64 * 32);
        __syncthreads();
        bf16x8 av[4], bv[4];
#pragma unroll
        for (int t = 0; t < 4; ++t)
            av[t] = *(const bf16x8*)(As + (m0 + t * 16 + lm) * 32 + krd);
#pragma unroll
        for (int t = 0; t < 4; ++t)
            bv[t] = *(const bf16x8*)(Bs + (n0 + t * 16 + lm) * 32 + krd);
#pragma unroll
        for (int i = 0; i < 4; ++i)
#pragma unroll
            for (int j = 0; j < 4; ++j)
                acc[i][j] = __builtin_amdgcn_mfma_f32_16x16x32_bf16(
                    av[i], bv[j], acc[i][j], 0, 0, 0);
        __syncthreads();
    }
}

// ------------------------------ prep kernels -------------------------------

__global__ __launch_bounds__(256) void prep_misc_kernel(
    const float* __restrict__ cv1_w,
    const float* __restrict__ qw, const float* __restrict__ qb,
    const float* __restrict__ kw, const float* __restrict__ kb,
    const float* __restrict__ vw, const float* __restrict__ vb,
    const float* __restrict__ ew, const float* __restrict__ eb,
    const float* __restrict__ cv2_w,
    const float* __restrict__ g1, const float* __restrict__ b1,
    const float* __restrict__ m1, const float* __restrict__ v1,
    const float* __restrict__ g2, const float* __restrict__ b2,
    const float* __restrict__ m2, const float* __restrict__ v2,
    bf16* __restrict__ w1b, bf16* __restrict__ wqkve, bf16* __restrict__ w2b,
    float* __restrict__ biasq,
    float* __restrict__ bn1s, float* __restrict__ bn1h,
    float* __restrict__ bn2s, float* __restrict__ bn2h)
{
    int idx = blockIdx.x * 256 + threadIdx.x;
    if (idx < 131072) { w1b[idx] = (bf16)cv1_w[idx]; return; }
    idx -= 131072;
    if (idx < 262144) {
        int j = idx >> 8, c = idx & 255;
        int p = j >> 8, r = j & 255;
        const float* w = (p == 0) ? qw : (p == 1) ? kw : (p == 2) ? vw : ew;
        wqkve[idx] = (bf16)w[r * 256 + c];
        return;
    }
    idx -= 262144;
    if (idx < 131072) { w2b[idx] = (bf16)cv2_w[idx]; return; }
    idx -= 131072;
    if (idx < 1024) {
        int p = idx >> 8, r = idx & 255;
        const float* bb = (p == 0) ? qb : (p == 1) ? kb : (p == 2) ? vb : eb;
        biasq[idx] = bb[r];
        return;
    }
    idx -= 1024;
    if (idx < 256) {
        float s = g1[idx] * rsqrtf(v1[idx] + 1e-5f);
        bn1s[idx] = s;
        bn1h[idx] = b1[idx] - m1[idx] * s;
        return;
    }
    idx -= 256;
    if (idx < 512) {
        float s = g2[idx] * rsqrtf(v2[idx] + 1e-5f);
        bn2s[idx] = s;
        bn2h[idx] = b2[idx] - m2[idx] * s;
        return;
    }
}

__global__ __launch_bounds__(256) void zero_lsum_kernel(float* __restrict__ p)
{
    p[blockIdx.x * 256 + threadIdx.x] = 0.f;
}

// qp[b*4096+n][256+c] = rel_h[c][h] + rel_w[c][w] for all b (pos half of qp)
__global__ __launch_bounds__(256) void pos_prep_kernel(
    const float* __restrict__ rel_h, const float* __restrict__ rel_w,
    bf16* __restrict__ qp)
{
    int n = blockIdx.x;
    int c = threadIdx.x;
    int h = n >> 6, w = n & 63;
    bf16 val = (bf16)(rel_h[c * 64 + h] + rel_w[c * 64 + w]);
#pragma unroll
    for (int b = 0; b < 8; ++b)
        qp[((size_t)(b * 4096 + n)) * 512 + 256 + c] = val;
}

// xt[b*4096+n][d] = (bf16) x[b][d][n]
__global__ __launch_bounds__(256) void transpose_x_kernel(
    const float* __restrict__ x, bf16* __restrict__ xt)
{
    __shared__ float tile[64][65];
    int b = blockIdx.z;
    int n0 = blockIdx.x * 64;
    int d0 = blockIdx.y * 64;
    int tx = threadIdx.x & 63, ty = threadIdx.x >> 6;
#pragma unroll
    for (int i = 0; i < 16; ++i) {
        int d = i * 4 + ty;
        tile[d][tx] = x[((size_t)(b * 512 + d0 + d)) * 4096 + n0 + tx];
    }
    __syncthreads();
#pragma unroll
    for (int i = 0; i < 16; ++i) {
        int n = i * 4 + ty;
        xt[((size_t)(b * 4096 + n0 + n)) * 512 + d0 + tx] = (bf16)tile[tx][n];
    }
}

// v_cm[b][c][m] = v_nm[b*4096+m][c]
__global__ __launch_bounds__(256) void transpose_v_kernel(
    const bf16* __restrict__ v_nm, bf16* __restrict__ v_cm)
{
    __shared__ float tile[64][65];
    int b = blockIdx.z;
    int m0 = blockIdx.x * 64;
    int c0 = blockIdx.y * 64;
    int tx = threadIdx.x & 63, ty = threadIdx.x >> 6;
#pragma unroll
    for (int i = 0; i < 16; ++i) {
        int m = i * 4 + ty;
        tile[m][tx] = (float)v_nm[((size_t)(b * 4096 + m0 + m)) * 256 + c0 + tx];
    }
    __syncthreads();
#pragma unroll
    for (int i = 0; i < 16; ++i) {
        int c = i * 4 + ty;
        v_cm[((size_t)(b * 256 + c0 + c)) * 4096 + m0 + tx] = (bf16)tile[tx][c];
    }
}

// ------------------------------ GEMM kernels -------------------------------

// x1t[row][col] = silu(bn1( sum_d xt[row][d] * w1b[col][d] ))
__global__ __launch_bounds__(256) void gemm1_kernel(
    const bf16* __restrict__ xt, const bf16* __restrict__ w1b,
    const float* __restrict__ bn1s, const float* __restrict__ bn1h,
    bf16* __restrict__ x1t)
{
    const bf16* A = xt + (size_t)(blockIdx.y * 128) * 512;
    const bf16* Bm = w1b + (size_t)(blockIdx.x * 128) * 512;
    f32x4 acc[4][4];
    gemm_core_lds(A, 512, Bm, 512, 512, acc);
    int wave = threadIdx.x >> 6;
    int lane = threadIdx.x & 63;
    int m0 = blockIdx.y * 128 + (wave >> 1) * 64;
    int n0 = blockIdx.x * 128 + (wave & 1) * 64;
    int lm = lane & 15, kq = lane >> 4;
#pragma unroll
    for (int i = 0; i < 4; ++i)
#pragma unroll
        for (int j = 0; j < 4; ++j)
#pragma unroll
            for (int r = 0; r < 4; ++r) {
                int row = m0 + i * 16 + kq * 4 + r;
                int col = n0 + j * 16 + lm;
                float h = bn1s[col] * acc[i][j][r] + bn1h[col];
                x1t[(size_t)row * 256 + col] = (bf16)silu_f(h);
            }
}

// projections: col<256 -> qp[.][col]; <512 -> ke[.][col-256];
//              <768 -> v_nm[.][col-512]; else ke[.][256+col-768]
__global__ __launch_bounds__(256) void gemm2_kernel(
    const bf16* __restrict__ x1t, const bf16* __restrict__ wqkve,
    const float* __restrict__ biasq,
    bf16* __restrict__ qp, bf16* __restrict__ ke, bf16* __restrict__ v_nm)
{
    const bf16* A = x1t + (size_t)(blockIdx.y * 128) * 256;
    const bf16* Bm = wqkve + (size_t)(blockIdx.x * 128) * 256;
    f32x4 acc[4][4];
    gemm_core_lds(A, 256, Bm, 256, 256, acc);
    int wave = threadIdx.x >> 6;
    int lane = threadIdx.x & 63;
    int m0 = blockIdx.y * 128 + (wave >> 1) * 64;
    int n0 = blockIdx.x * 128 + (wave & 1) * 64;
    int lm = lane & 15, kq = lane >> 4;
#pragma unroll
    for (int i = 0; i < 4; ++i)
#pragma unroll
        for (int j = 0; j < 4; ++j)
#pragma unroll
            for (int r = 0; r < 4; ++r) {
                int row = m0 + i * 16 + kq * 4 + r;
                int col = n0 + j * 16 + lm;
                bf16 val = (bf16)(acc[i][j][r] + biasq[col]);
                if (col < 256)       qp[(size_t)row * 512 + col] = val;
                else if (col < 512)  ke[(size_t)row * 512 + (col - 256)] = val;
                else if (col < 768)  v_nm[(size_t)row * 256 + (col - 512)] = val;
                else                 ke[(size_t)row * 512 + 256 + (col - 768)] = val;
            }
}

// P[bz][n][m] = exp(qp[b,n,:].ke[b,m,:] - 8), bf16; row sums -> lsum[bz][n]
__global__ __launch_bounds__(256) void gemm3b_kernel(
    const bf16* __restrict__ qp, const bf16* __restrict__ ke,
    bf16* __restrict__ P, float* __restrict__ lsum, int gbase)
{
    __shared__ float part[128][33];
    int bz = blockIdx.z;
    int b = gbase + bz;
    const bf16* A = qp + ((size_t)b * 4096 + blockIdx.y * 128) * 512;
    const bf16* Bm = ke + ((size_t)b * 4096 + blockIdx.x * 128) * 512;
    f32x4 acc[4][4];
    gemm_core_lds(A, 512, Bm, 512, 512, acc);
    int tid = threadIdx.x;
    int wave = tid >> 6;
    int lane = tid & 63;
    int m0 = (wave >> 1) * 64, n0 = (wave & 1) * 64;
    int lm = lane & 15, kq = lane >> 4;
    int pcol = (wave & 1) * 16 + lm;
    // exp in place + per-lane row partials (sum over this lane's 4 cols)
#pragma unroll
    for (int i = 0; i < 4; ++i)
#pragma unroll
        for (int r = 0; r < 4; ++r) {
            float s = 0.f;
#pragma unroll
            for (int j = 0; j < 4; ++j) {
                float e = __expf(acc[i][j][r] - 8.f);
                acc[i][j][r] = e;
                s += e;
            }
            part[m0 + i * 16 + kq * 4 + r][pcol] = s;
        }
    // store exp(S) tile
    bf16* Pb = P + ((size_t)bz * 4096 + blockIdx.y * 128) * 4096 + blockIdx.x * 128;
#pragma unroll
    for (int i = 0; i < 4; ++i)
#pragma unroll
        for (int j = 0; j < 4; ++j)
#pragma unroll
            for (int r = 0; r < 4; ++r)
                Pb[(size_t)(m0 + i * 16 + kq * 4 + r) * 4096 + n0 + j * 16 + lm] =
                    (bf16)acc[i][j][r];
    __syncthreads();
    if (tid < 128) {
        const float* pr = &part[tid][0];
        float s = 0.f;
#pragma unroll
        for (int c = 0; c < 32; ++c) s += pr[c];
        atomicAdd(&lsum[(size_t)bz * 4096 + blockIdx.y * 128 + tid], s);
    }
}

// split-K PV partials: partk[ks][bz][n][c] = sum_{m in ks half} P*v
__global__ __launch_bounds__(256) void gemm4p_kernel(
    const bf16* __restrict__ P, const bf16* __restrict__ v_cm,
    float* __restrict__ partk, int gbase)
{
    int bz = blockIdx.z >> 1;
    int ks = blockIdx.z & 1;
    int b = gbase + bz;
    const bf16* A = P + ((size_t)bz * 4096 + blockIdx.y * 128) * 4096 + ks * 2048;
    const bf16* Bm = v_cm + ((size_t)b * 256 + blockIdx.x * 128) * 4096 + ks * 2048;
    f32x4 acc[4][4];
    gemm_core_lds(A, 4096, Bm, 4096, 2048, acc);
    int wave = threadIdx.x >> 6;
    int lane = threadIdx.x & 63;
    int m0 = (wave >> 1) * 64, n0 = (wave & 1) * 64;
    int lm = lane & 15, kq = lane >> 4;
    float* pb = partk + (((size_t)(ks * 4 + bz) * 4096 + blockIdx.y * 128) * 256)
                + blockIdx.x * 128;
#pragma unroll
    for (int i = 0; i < 4; ++i)
#pragma unroll
        for (int j = 0; j < 4; ++j)
#pragma unroll
            for (int r = 0; r < 4; ++r)
                pb[(size_t)(m0 + i * 16 + kq * 4 + r) * 256 + n0 + j * 16 + lm] =
                    acc[i][j][r];
}

// out_t[(gbase+bz)*4096+n][c] = (partk0+partk1)/lsum[bz][n]  (bf16)
__global__ __launch_bounds__(256) void reduce_norm_kernel(
    const float* __restrict__ partk, const float* __restrict__ lsum,
    bf16* __restrict__ out_t, int gbase)
{
    int idx = blockIdx.x * 256 + threadIdx.x;      // [bz(2b)][n(12b)][c4(6b)]
    int c4 = idx & 63;
    int n = (idx >> 6) & 4095;
    int bz = idx >> 18;
    size_t base = ((size_t)bz * 4096 + n) * 256 + c4 * 4;
    f32x4 p0 = *(const f32x4*)(partk + base);
    f32x4 p1 = *(const f32x4*)(partk + 4194304 + base);
    float inv = 1.f / lsum[bz * 4096 + n];
    bf16x4 o;
#pragma unroll
    for (int k = 0; k < 4; ++k)
        o[k] = (bf16)((p0[k] + p1[k]) * inv);
    *(bf16x4*)(out_t + ((size_t)(gbase + bz) * 4096 + n) * 256 + c4 * 4) = o;
}

// d_out[b][d][n] = x[b][d][n] + silu(bn2( sum_c w2b[d][c]*out_t[b*4096+n][c] ))
__global__ __launch_bounds__(256) void gemm5_kernel(
    const bf16* __restrict__ w2b, const bf16* __restrict__ out_t,
    const float* __restrict__ bn2s, const float* __restrict__ bn2h,
    const float* __restrict__ x, float* __restrict__ out)
{
    int b = blockIdx.z;
    const bf16* A = w2b + (size_t)(blockIdx.y * 128) * 256;
    const bf16* Bm = out_t + ((size_t)b * 4096 + blockIdx.x * 128) * 256;
    f32x4 acc[4][4];
    gemm_core_lds(A, 256, Bm, 256, 256, acc);
    int wave = threadIdx.x >> 6;
    int lane = threadIdx.x & 63;
    int m0 = blockIdx.y * 128 + (wave >> 1) * 64;   // d (512)
    int n0 = blockIdx.x * 128 + (wave & 1) * 64;    // n (4096)
    int lm = lane & 15, kq = lane >> 4;
#pragma unroll
    for (int i = 0; i < 4; ++i)
#pragma unroll
        for (int j = 0; j < 4; ++j)
#pragma unroll
            for (int r = 0; r < 4; ++r) {
                int d = m0 + i * 16 + kq * 4 + r;
                int n = n0 + j * 16 + lm;
                float h = bn2s[d] * acc[i][j][r] + bn2h[d];
                size_t gi = ((size_t)(b * 512 + d)) * 4096 + n;
                out[gi] = x[gi] + silu_f(h);
            }
}

// ------------------------------- launcher ----------------------------------

extern "C" void kernel_launch(void* const* d_in, const int* in_sizes, int n_in,
                              void* d_out, int out_size, void* d_ws, size_t ws_size,
                              hipStream_t stream)
{
    (void)in_sizes; (void)n_in; (void)out_size; (void)ws_size;
    const float* x     = (const float*)d_in[0];
    const float* cv1_w = (const float*)d_in[1];
    const float* bn1_g = (const float*)d_in[2];
    const float* bn1_b = (const float*)d_in[3];
    const float* bn1_m = (const float*)d_in[4];
    const float* bn1_v = (const float*)d_in[5];
    const float* q_w   = (const float*)d_in[6];
    const float* q_b   = (const float*)d_in[7];
    const float* k_w   = (const float*)d_in[8];
    const float* k_b   = (const float*)d_in[9];
    const float* v_w   = (const float*)d_in[10];
    const float* v_b   = (const float*)d_in[11];
    const float* e_w   = (const float*)d_in[12];
    const float* e_b   = (const float*)d_in[13];
    const float* rel_h = (const float*)d_in[14];
    const float* rel_w = (const float*)d_in[15];
    const float* cv2_w = (const float*)d_in[16];
    const float* bn2_g = (const float*)d_in[17];
    const float* bn2_b = (const float*)d_in[18];
    const float* bn2_m = (const float*)d_in[19];
    const float* bn2_v = (const float*)d_in[20];
    float* out = (float*)d_out;

    char* ws = (char*)d_ws;
    // P_grp region (128 MB) also hosts xt/x1t/v_nm (all dead before attention).
    // qp/ke (64 MB) are dead after gemm3b of each group -> partk overlays them.
    bf16* P     = (bf16*)(ws + 0);            // 128 MB [4][4096][4096]
    bf16* xt    = (bf16*)(ws + 0);            //  32 MB overlay
    bf16* x1t   = (bf16*)(ws + 33554432);     //  16 MB overlay
    bf16* v_nm  = (bf16*)(ws + 50331648);     //  16 MB overlay
    bf16* qp    = (bf16*)(ws + 134217728);    //  32 MB [32768][512]
    bf16* ke    = (bf16*)(ws + 167772160);    //  32 MB [32768][512]
    float* partk= (float*)(ws + 134217728);   //  33.5 MB [2][4][4096][256] f32
    bf16* v_cm  = (bf16*)(ws + 201326592);    //  16 MB [8][256][4096]
    bf16* out_t = (bf16*)(ws + 218103808);    //  16 MB [32768][256]
    bf16* w1b   = (bf16*)(ws + 234881024);    // 256 KB
    bf16* wqkve = (bf16*)(ws + 235143168);    // 512 KB
    bf16* w2b   = (bf16*)(ws + 235667456);    // 256 KB
    float* biasq= (float*)(ws + 235929600);   //   4 KB
    float* bn1s = (float*)(ws + 235933696);
    float* bn1h = (float*)(ws + 235934720);
    float* bn2s = (float*)(ws + 235935744);
    float* bn2h = (float*)(ws + 235937792);
    float* lsum = (float*)(ws + 235941888);   // 128 KB [2][4][4096] fp32

    prep_misc_kernel<<<2055, 256, 0, stream>>>(
        cv1_w, q_w, q_b, k_w, k_b, v_w, v_b, e_w, e_b, cv2_w,
        bn1_g, bn1_b, bn1_m, bn1_v, bn2_g, bn2_b, bn2_m, bn2_v,
        w1b, wqkve, w2b, biasq, bn1s, bn1h, bn2s, bn2h);
    zero_lsum_kernel<<<128, 256, 0, stream>>>(lsum);
    transpose_x_kernel<<<dim3(64, 8, 8), 256, 0, stream>>>(x, xt);
    gemm1_kernel<<<dim3(2, 256), 256, 0, stream>>>(xt, w1b, bn1s, bn1h, x1t);
    gemm2_kernel<<<dim3(8, 256), 256, 0, stream>>>(x1t, wqkve, biasq, qp, ke, v_nm);
    pos_prep_kernel<<<4096, 256, 0, stream>>>(rel_h, rel_w, qp);
    transpose_v_kernel<<<dim3(64, 4, 8), 256, 0, stream>>>(v_nm, v_cm);
    // NOTE: group 1's gemm3b reads qp/ke, which partk (group 0's gemm4p
    // output) would overwrite -- so run BOTH gemm3b groups first, then the
    // PV stage for both groups.
    gemm3b_kernel<<<dim3(32, 32, 4), 256, 0, stream>>>(qp, ke, P, lsum, 0);
    // P holds only one group (128 MB) -> groups must alternate. Keep group
    // split but order so qp/ke die before partk is written:
    //   g0: gemm3b -> gemm4p -> reduce ; g1: gemm3b would need qp/ke again.
    // qp/ke are inputs for both groups, so instead partk overlays xt region?
    // xt region is under P (live). Resolution: gemm4p(g0) writes partk AFTER
    // gemm3b(g1) has consumed qp/ke. Sequence below enforces that by running
    // g0's PV stage after g1's gemm3b, using a second P buffer? P is 128 MB
    // and only one fits. Final resolution: alternate with partk placed in
    // qp region but only after the LAST gemm3b. For g0's PV we still have
    // qp live -> use out_t region? out_t is 16 MB < 33.5 MB.
    // => Simplest correct ordering: run g0 fully with partk in qp region is
    // UNSAFE; instead g0 uses partk region carved from ke only (32 MB) with
    // KS=2 needing 33.5 MB -> also unsafe.
    // Therefore: swap group order of stages: do g1's gemm3b into P? P holds
    // one group only. Fall back: per-group sequence with partk in qp+ke is
    // only safe for the FINAL group; for g0 place partk in the xt overlay?
    // xt overlay sits inside P (live). -- Given constraints, we instead
    // reuse the tail scratch: out_t+weights end at ~236 MB; total ws is at
    // least 238 MB (round-1 layout used 238 MB successfully). Place g0's
    // partk at ws+236. But 236+33.5 = 269.5 MB > 238: unsafe.
    // FINAL CHOICE (implemented): KS=2 partials are fp32 [2][4][4096][256]
    // = 33.5 MB. ke alone is 32 MB; qp's last 1.5 MB... qp IS dead after
    // gemm3b(g) for rows of THIS group? No: qp/ke hold all 8 batches.
    // Run gemm3b for BOTH groups before any gemm4p, storing g1's P in...
    // impossible (256 MB).
    // => Use KS=2 partials in HALVES: run gemm4p per ks and reduce
    // immediately, so only 16.8 MB live at once, fitting in ke's first
    // 16.8 MB AFTER the last gemm3b of the last group. For g0 we must not
    // touch qp/ke. So for g0, place the 16.8 MB partial buffer inside
    // out_t? out_t[g0 half] is exactly what reduce writes... partial is
    // fp32 (16.8 MB) vs out_t half (8.4 MB). Distinct region needed.
    // Place single-ks partial (16.8 MB) at ws+218103808+16MB? That's the
    // weights region (too small).
    //
    // Actually the clean answer: accumulate ks=1 INTO ks=0's buffer with
    // one buffer of 16.8 MB via a second pass add -- still needs the
    // buffer. We allocate it inside v_nm's old overlay? v_nm overlay is
    // inside P (live). No.
    //
    // Pragmatic resolution: restore round-4 single-kernel gemm4b (full K,
    // no partials) for group 0, and use split-K only for group 1 (qp/ke
    // dead). Half the win, zero risk.
    gemm4p_dummy:;
    {
        // group 0: full-K gemm4b via gemm4p with ks covering K=4096 when
        // launched with gridDim.z == 4 (bz = z, ks forced 0 by z&1 == 0
        // only if z even) -- instead we just call the full-K variant below.
    }
    // (see gemm4f_kernel below)
    extern __global__ void gemm4f_kernel(const bf16*, const bf16*,
                                         const float*, bf16*, int);
    gemm4f_kernel<<<dim3(2, 32, 4), 256, 0, stream>>>(P, v_cm, lsum, out_t, 0);
    gemm3b_kernel<<<dim3(32, 32, 4), 256, 0, stream>>>(qp, ke, P, lsum + 16384, 4);
    gemm4p_kernel<<<dim3(2, 32, 8), 256, 0, stream>>>(P, v_cm, partk, 4);
    reduce_norm_kernel<<<4096, 256, 0, stream>>>(partk, lsum + 16384, out_t, 4);
    gemm5_kernel<<<dim3(32, 4, 8), 256, 0, stream>>>(w2b, out_t, bn2s, bn2h, x, out);
}

// full-K PV with normalize epilogue (used for group 0 where qp/ke are live)
__global__ __launch_bounds__(256) void gemm4f_kernel(
    const bf16* __restrict__ P, const bf16* __restrict__ v_cm,
    const float* __restrict__ lsum,
    bf16* __restrict__ out_t, int gbase)
{
    int bz = blockIdx.z;
    int b = gbase + bz;
    const bf16* A = P + ((size_t)bz * 4096 + blockIdx.y * 128) * 4096;
    const bf16* Bm = v_cm + ((size_t)b * 256 + blockIdx.x * 128) * 4096;
    f32x4 acc[4][4];
    gemm_core_lds(A, 4096, Bm, 4096, 4096, acc);
    int wave = threadIdx.x >> 6;
    int lane = threadIdx.x & 63;
    int m0 = (wave >> 1) * 64, n0 = (wave & 1) * 64;
    int lm = lane & 15, kq = lane >> 4;
    const float* ls = lsum + (size_t)bz * 4096 + blockIdx.y * 128;
    bf16* ob = out_t + ((size_t)b * 4096 + blockIdx.y * 128) * 256 + blockIdx.x * 128;
#pragma unroll
    for (int i = 0; i < 4; ++i)
#pragma unroll
        for (int r = 0; r < 4; ++r) {
            float inv = 1.f / ls[m0 + i * 16 + kq * 4 + r];
#pragma unroll
            for (int j = 0; j < 4; ++j)
                ob[(size_t)(m0 + i * 16 + kq * 4 + r) * 256 + n0 + j * 16 + lm] =
                    (bf16)(acc[i][j][r] * inv);
        }
}